// Round 4
// baseline (756.557 us; speedup 1.0000x reference)
//
#include <hip/hip_runtime.h>

#define B_   32
#define NQ_  4096
#define NK_  77
#define H_   8
#define DH_  40
#define IN_  320
#define CD_  768
#define M_   (B_ * NQ_)   // 131072 rows
#define MKV_ (B_ * NK_)   // 2464 context rows

#define NKP_  80    // keys padded for score n-tiles
#define NKP2_ 96    // keys padded for PV k-steps
#define DHP_  48    // dims padded for PV n-tiles
#define KQ_   64    // qk k-dim padded (40 -> 64)

typedef __attribute__((ext_vector_type(8))) short bf16x8;
typedef __attribute__((ext_vector_type(4))) float f32x4;
typedef unsigned short ushort_t;

__device__ __forceinline__ unsigned short f2bf(float f) {
  union { float f; unsigned int i; } v; v.f = f;
  unsigned int i = v.i;
  i += 0x7fffu + ((i >> 16) & 1u);   // round-to-nearest-even
  return (unsigned short)(i >> 16);
}
__device__ __forceinline__ unsigned int pack2(float a, float b) {
  return (unsigned int)f2bf(a) | ((unsigned int)f2bf(b) << 16);
}

// ---------------------------------------------------------------------------
// Convert weights to bf16 once. blockIdx.y: 0=Wq(320x320), 1=Wo(320x320),
// 2=Wk(320x768), 3=Wv(320x768).
// ---------------------------------------------------------------------------
__global__ __launch_bounds__(256) void wcvt(
    const float* __restrict__ Wq, const float* __restrict__ Wo,
    const float* __restrict__ Wk, const float* __restrict__ Wv,
    unsigned short* __restrict__ Wqb, unsigned short* __restrict__ Wob,
    unsigned short* __restrict__ Wkb, unsigned short* __restrict__ Wvb)
{
  const int i = blockIdx.x * 256 + threadIdx.x;   // float4 index
  const float* src;
  unsigned short* dst;
  int n;
  switch (blockIdx.y) {
    case 0:  src = Wq; dst = Wqb; n = IN_ * IN_ / 4; break;   // 25600
    case 1:  src = Wo; dst = Wob; n = IN_ * IN_ / 4; break;   // 25600
    case 2:  src = Wk; dst = Wkb; n = IN_ * CD_ / 4; break;   // 61440
    default: src = Wv; dst = Wvb; n = IN_ * CD_ / 4; break;   // 61440
  }
  if (i >= n) return;
  const float4 v = ((const float4*)src)[i];
  uint2 p; p.x = pack2(v.x, v.y); p.y = pack2(v.z, v.w);
  ((uint2*)dst)[i] = p;
}

// ---------------------------------------------------------------------------
// K/V projection as MFMA GEMM.
// C[2464,320] = ctx[2464,768] @ W[320,768]^T, tile 64x64, BK=32, row-guarded
// to M=2496. blockIdx.z: 0 -> K (scatter into Khb), 1 -> V (scatter into Vtb).
//   Khb: [B, H, 80, 64] bf16   (K rows; rows>=77 and cols>=40 stay zero)
//   Vtb: [B, H, 48, 96] bf16   (V transposed; rows>=40 and cols>=77 stay zero)
// Buffers pre-zeroed with hipMemsetAsync; epilogue fuses gamma + layout.
// ---------------------------------------------------------------------------
__global__ __launch_bounds__(256) void kv_mfma(
    const float* __restrict__ ctx, const unsigned short* __restrict__ Wkb,
    const unsigned short* __restrict__ Wvb, const float* __restrict__ gk,
    const float* __restrict__ gv, unsigned short* __restrict__ Khb,
    unsigned short* __restrict__ Vtb)
{
  constexpr int LDA = 40;   // bf16 elems per LDS row (32 + 8 pad)
  __shared__ alignas(16) unsigned short As[64 * LDA];
  __shared__ alignas(16) unsigned short Bs[64 * LDA];
  const int m0 = blockIdx.x * 64;       // 39 tiles cover 2496 >= 2464
  const int n0 = blockIdx.y * 64;       // 5 tiles cover 320
  const int isV = blockIdx.z;
  const unsigned short* Wb = isV ? Wvb : Wkb;
  const int tid = threadIdx.x;
  const int wave = tid >> 6;
  const int lane = tid & 63;
  const int lm = lane & 15;
  const int quad = lane >> 4;

  f32x4 acc0 = {0.f, 0.f, 0.f, 0.f};
  f32x4 acc1 = acc0, acc2 = acc0, acc3 = acc0;

  for (int k0 = 0; k0 < CD_; k0 += 32) {
    // stage A: 64 rows x 32 k, fp32 -> bf16, zero rows >= 2464
#pragma unroll
    for (int c = tid; c < 512; c += 256) {
      const int row = c >> 3, kq = (c & 7) << 2;
      const int fr = m0 + row;
      float4 v = {0.f, 0.f, 0.f, 0.f};
      if (fr < MKV_)
        v = *(const float4*)(ctx + (size_t)fr * CD_ + k0 + kq);
      uint2 p; p.x = pack2(v.x, v.y); p.y = pack2(v.z, v.w);
      *(uint2*)(&As[row * LDA + kq]) = p;
    }
    // stage B: 64 W rows x 32 k (bf16, contiguous uint4)
    {
      const int row = tid >> 2, kq = (tid & 3) << 3;
      *(uint4*)(&Bs[row * LDA + kq]) =
          *(const uint4*)(Wb + (size_t)(n0 + row) * CD_ + k0 + kq);
    }
    __syncthreads();
    const bf16x8 a  = *(const bf16x8*)(&As[(wave * 16 + lm) * LDA + quad * 8]);
    const bf16x8 b0 = *(const bf16x8*)(&Bs[( 0 + lm) * LDA + quad * 8]);
    const bf16x8 b1 = *(const bf16x8*)(&Bs[(16 + lm) * LDA + quad * 8]);
    const bf16x8 b2 = *(const bf16x8*)(&Bs[(32 + lm) * LDA + quad * 8]);
    const bf16x8 b3 = *(const bf16x8*)(&Bs[(48 + lm) * LDA + quad * 8]);
    acc0 = __builtin_amdgcn_mfma_f32_16x16x32_bf16(a, b0, acc0, 0, 0, 0);
    acc1 = __builtin_amdgcn_mfma_f32_16x16x32_bf16(a, b1, acc1, 0, 0, 0);
    acc2 = __builtin_amdgcn_mfma_f32_16x16x32_bf16(a, b2, acc2, 0, 0, 0);
    acc3 = __builtin_amdgcn_mfma_f32_16x16x32_bf16(a, b3, acc3, 0, 0, 0);
    __syncthreads();
  }

  const float* g = isV ? gv : gk;
  const f32x4 accs[4] = {acc0, acc1, acc2, acc3};
#pragma unroll
  for (int t = 0; t < 4; ++t) {
    const int col = n0 + t * 16 + lm;
    const int h = col / DH_, d = col % DH_;
    const float gc = g[col];
#pragma unroll
    for (int r = 0; r < 4; ++r) {
      const int row = m0 + wave * 16 + quad * 4 + r;
      if (row < MKV_) {
        const int bb = row / NK_, pos = row % NK_;
        const unsigned short val = f2bf(accs[t][r] * gc);
        if (!isV)
          Khb[((size_t)(bb * H_ + h) * NKP_ + pos) * KQ_ + d] = val;
        else
          Vtb[((size_t)(bb * H_ + h) * DHP_ + d) * NKP2_ + pos] = val;
      }
    }
  }
}

// ---------------------------------------------------------------------------
// Strip GEMM v3: C[M,320] = A[M,320] @ W[320,320]^T.
// One block = 64 rows x full 320 cols; A fetched exactly once (40 VGPR of
// A-frags per lane, small enough that the compiler keeps them live).
// B goes through LDS in FRAGMENT-MAJOR layout: frag (nf,kf) occupies 64
// consecutive 16B lane-slots -> ds_write_b128 and ds_read_b128 are both
// fully contiguous per wave (zero bank conflicts). Chunk nc+1's global
// loads are issued BEFORE computing chunk nc (register prefetch), so the
// barrier drain at the next iteration waits on loads that are ~a full
// compute-phase old. LDS 40 KB + __launch_bounds__(256,4) -> 4 blocks/CU.
// MODE 0: A = x fp32 (convert in regs), C = Q bf16, *gamma.
// MODE 1: A = O bf16 (ws), C = d_out fp32, (+bias)*gamma.
// ---------------------------------------------------------------------------
template <int MODE>
__global__ __launch_bounds__(256, 4) void gemm_strip(
    const void* __restrict__ Ap, const unsigned short* __restrict__ Wb,
    const float* __restrict__ gamma, const float* __restrict__ bias,
    void* __restrict__ Cp)
{
  __shared__ alignas(16) unsigned short Bs[40 * 64 * 8];   // 40 KB, frag-major
  const int m0 = blockIdx.x * 64;
  const int tid = threadIdx.x;
  const int wave = tid >> 6;
  const int lane = tid & 63;
  const int lm = lane & 15;
  const int quad = lane >> 4;
  const int arow = m0 + wave * 16 + lm;

  // staging coords: thread stages 10 x 16B of W row sr (chunk-relative),
  // 16B-chunk indices sc, sc+4, ..., sc+36.
  const int sr = tid >> 2;
  const int sc = tid & 3;
  const int snf = sr >> 4;
  const int slm = sr & 15;

  // ---- prefetch B chunk 0 into registers ----
  uint4 rB[10];
  {
    const unsigned short* src = Wb + (size_t)sr * IN_;
#pragma unroll
    for (int j = 0; j < 10; ++j)
      rB[j] = *(const uint4*)(src + (sc + j * 4) * 8);
  }

  // ---- A fragments: full K=320 in registers (10 frags = 40 VGPR) ----
  bf16x8 a[10];
  if (MODE == 0) {
    const float* A = (const float*)Ap;
    const float* rp = A + (size_t)arow * IN_ + quad * 8;
#pragma unroll
    for (int kf = 0; kf < 10; ++kf) {
      const float4 v0 = *(const float4*)(rp + kf * 32);
      const float4 v1 = *(const float4*)(rp + kf * 32 + 4);
      union { uint4 u; bf16x8 h; } cv;
      cv.u.x = pack2(v0.x, v0.y); cv.u.y = pack2(v0.z, v0.w);
      cv.u.z = pack2(v1.x, v1.y); cv.u.w = pack2(v1.z, v1.w);
      a[kf] = cv.h;
    }
  } else {
    const unsigned short* A = (const unsigned short*)Ap;
    const unsigned short* rp = A + (size_t)arow * IN_ + quad * 8;
#pragma unroll
    for (int kf = 0; kf < 10; ++kf)
      a[kf] = *(const bf16x8*)(rp + kf * 32);
  }

  for (int nc = 0; nc < 5; ++nc) {
    if (nc) __syncthreads();          // all waves done reading chunk nc-1
    // regs -> LDS, fragment-major: frag (snf, j), lane-slot sc*16+slm.
    // Per wave this is 64 consecutive 16B slots per j -> conflict-free.
#pragma unroll
    for (int j = 0; j < 10; ++j)
      *(uint4*)(&Bs[(((snf * 10) + j) * 64 + sc * 16 + slm) * 8]) = rB[j];
    __syncthreads();
    // issue next chunk's global loads now; they land during compute below
    if (nc < 4) {
      const unsigned short* src = Wb + (size_t)((nc + 1) * 64 + sr) * IN_;
#pragma unroll
      for (int j = 0; j < 10; ++j)
        rB[j] = *(const uint4*)(src + (sc + j * 4) * 8);
    }

    f32x4 acc[4];
#pragma unroll
    for (int nf = 0; nf < 4; ++nf) acc[nf] = (f32x4){0.f, 0.f, 0.f, 0.f};
#pragma unroll
    for (int kf = 0; kf < 10; ++kf) {
#pragma unroll
      for (int nf = 0; nf < 4; ++nf) {
        const bf16x8 b =
            *(const bf16x8*)(&Bs[((nf * 10 + kf) * 64 + lane) * 8]);
        acc[nf] = __builtin_amdgcn_mfma_f32_16x16x32_bf16(a[kf], b, acc[nf], 0, 0, 0);
      }
    }

    // ---- epilogue for this 64-col chunk ----
#pragma unroll
    for (int nf = 0; nf < 4; ++nf) {
      const int col = nc * 64 + nf * 16 + lm;
      const float g = gamma[col];
      if (MODE == 0) {
#pragma unroll
        for (int r = 0; r < 4; ++r) {
          const int row = m0 + wave * 16 + quad * 4 + r;
          ((unsigned short*)Cp)[(size_t)row * IN_ + col] = f2bf(acc[nf][r] * g);
        }
      } else {
        const float bbv = bias[col];
#pragma unroll
        for (int r = 0; r < 4; ++r) {
          const int row = m0 + wave * 16 + quad * 4 + r;
          ((float*)Cp)[(size_t)row * IN_ + col] = (acc[nf][r] + bbv) * g;
        }
      }
    }
  }
}

// ---------------------------------------------------------------------------
// MFMA attention. Block = 256 thr (4 waves) handles (b, h, 128 q rows);
// each wave owns 32 rows (2 m-frags). S = Q.K^T (k 40->64), softmax in regs
// (shfl_xor over the 16 col-lanes), P -> LDS (C-layout -> A-layout), P.V with
// keys padded to 96 against V^T. O overwrites Q slice in ws (bf16).
// LDS: Qs[128x72] + Ks[80x72] overlaid later by Ps[4][32x104]; Vt[48x104].
// ---------------------------------------------------------------------------
#define QT_ 128
__global__ __launch_bounds__(256) void attn_mfma(
    const unsigned short* __restrict__ Khb,
    const unsigned short* __restrict__ Vtb,
    unsigned short* __restrict__ QO)
{
  __shared__ alignas(16) unsigned short smem[14976 + 48 * 104];
  unsigned short* Qs = smem;            // 128 x 72
  unsigned short* Ks = smem + 128 * 72; // 80 x 72
  unsigned short* Vt = smem + 14976;    // 48 x 104
  unsigned short* Ps = smem;            // overlays Qs/Ks: wave w at w*32*104

  const int b = blockIdx.z, h = blockIdx.y, qt = blockIdx.x;
  const int tid = threadIdx.x;
  const int row0 = qt * QT_;
  const size_t qbase = ((size_t)b * NQ_ + row0) * IN_ + h * DH_;

  // ---- stage Q (bf16, zero-pad cols 40..71) ----
  for (int i = tid; i < QT_ * 9; i += 256) {
    const int row = i / 9, seg = i % 9;
    uint4 v = {0u, 0u, 0u, 0u};
    if (seg < 5)
      v = *(const uint4*)(QO + qbase + (size_t)row * IN_ + seg * 8);
    *(uint4*)(&Qs[row * 72 + seg * 8]) = v;
  }
  // ---- stage K [80x64] -> [80x72] (zero-pad cols 64..71) ----
  {
    const unsigned short* src = Khb + (size_t)(b * H_ + h) * NKP_ * KQ_;
    for (int i = tid; i < NKP_ * 9; i += 256) {
      const int row = i / 9, seg = i % 9;
      uint4 v = {0u, 0u, 0u, 0u};
      if (seg < 8) v = *(const uint4*)(src + row * KQ_ + seg * 8);
      *(uint4*)(&Ks[row * 72 + seg * 8]) = v;
    }
  }
  // ---- stage V^T [48x96] -> [48x104] (cols 96..103 never read) ----
  {
    const unsigned short* src = Vtb + (size_t)(b * H_ + h) * DHP_ * NKP2_;
    for (int i = tid; i < DHP_ * 12; i += 256) {
      const int row = i / 12, seg = i % 12;
      *(uint4*)(&Vt[row * 104 + seg * 8]) =
          *(const uint4*)(src + row * NKP2_ + seg * 8);
    }
  }
  __syncthreads();

  const int wave = tid >> 6;
  const int lane = tid & 63;
  const int lm = lane & 15;
  const int quad = lane >> 4;
  const int wrow = wave * 32;   // wave's 32-row window within the 128-row tile

  // ---- S = Q.K^T ----
  f32x4 sacc[2][5];
#pragma unroll
  for (int mf = 0; mf < 2; ++mf)
#pragma unroll
    for (int t = 0; t < 5; ++t) sacc[mf][t] = (f32x4){0.f, 0.f, 0.f, 0.f};

#pragma unroll
  for (int k = 0; k < 2; ++k) {
    bf16x8 aq[2];
#pragma unroll
    for (int mf = 0; mf < 2; ++mf)
      aq[mf] = *(const bf16x8*)(&Qs[(wrow + mf * 16 + lm) * 72 + k * 32 + quad * 8]);
#pragma unroll
    for (int t = 0; t < 5; ++t) {
      const bf16x8 bk = *(const bf16x8*)(&Ks[(t * 16 + lm) * 72 + k * 32 + quad * 8]);
#pragma unroll
      for (int mf = 0; mf < 2; ++mf)
        sacc[mf][t] = __builtin_amdgcn_mfma_f32_16x16x32_bf16(aq[mf], bk, sacc[mf][t], 0, 0, 0);
    }
  }

  // ---- softmax (rows = quad*4+r within each 16-row m-frag) ----
  const float scale = 0.15811388300841897f;   // 1/sqrt(40)
  float sv[2][5][4];
  float rl[2][4];
#pragma unroll
  for (int mf = 0; mf < 2; ++mf) {
#pragma unroll
    for (int t = 0; t < 5; ++t)
#pragma unroll
      for (int r = 0; r < 4; ++r) {
        float v = sacc[mf][t][r] * scale;
        if (t == 4 && lm >= 13) v = -1e30f;   // mask keys 77..79
        sv[mf][t][r] = v;
      }
#pragma unroll
    for (int r = 0; r < 4; ++r) {
      float m = sv[mf][0][r];
#pragma unroll
      for (int t = 1; t < 5; ++t) m = fmaxf(m, sv[mf][t][r]);
#pragma unroll
      for (int d = 1; d < 16; d <<= 1) m = fmaxf(m, __shfl_xor(m, d));
      float l = 0.f;
#pragma unroll
      for (int t = 0; t < 5; ++t) {
        const float e = __expf(sv[mf][t][r] - m);
        sv[mf][t][r] = e;
        l += e;
      }
#pragma unroll
      for (int d = 1; d < 16; d <<= 1) l += __shfl_xor(l, d);
      rl[mf][r] = 1.f / l;
    }
  }

  __syncthreads();   // all S-phase reads of Qs/Ks done before Ps overlay

  // ---- P -> LDS (A-layout source), zero cols 80..95 (keys pad for PV) ----
  unsigned short* Pw = Ps + wave * 32 * 104;
#pragma unroll
  for (int mf = 0; mf < 2; ++mf)
#pragma unroll
    for (int t = 0; t < 5; ++t)
#pragma unroll
      for (int r = 0; r < 4; ++r)
        Pw[(mf * 16 + quad * 4 + r) * 104 + t * 16 + lm] = f2bf(sv[mf][t][r]);
  {
    const int row = lane >> 1, half = lane & 1;
    *(uint4*)(&Pw[row * 104 + 80 + half * 8]) = (uint4){0u, 0u, 0u, 0u};
  }
  __syncthreads();

  // ---- O = P.V  (K = 96 keys, N = 48 dims) ----
  f32x4 oacc[2][3];
#pragma unroll
  for (int mf = 0; mf < 2; ++mf)
#pragma unroll
    for (int n = 0; n < 3; ++n) oacc[mf][n] = (f32x4){0.f, 0.f, 0.f, 0.f};

#pragma unroll
  for (int k = 0; k < 3; ++k) {
    bf16x8 ap[2];
#pragma unroll
    for (int mf = 0; mf < 2; ++mf)
      ap[mf] = *(const bf16x8*)(&Pw[(mf * 16 + lm) * 104 + k * 32 + quad * 8]);
#pragma unroll
    for (int n = 0; n < 3; ++n) {
      const bf16x8 bv = *(const bf16x8*)(&Vt[(n * 16 + lm) * 104 + k * 32 + quad * 8]);
#pragma unroll
      for (int mf = 0; mf < 2; ++mf)
        oacc[mf][n] = __builtin_amdgcn_mfma_f32_16x16x32_bf16(ap[mf], bv, oacc[mf][n], 0, 0, 0);
    }
  }

  // ---- store O (bf16) over the Q slice ----
#pragma unroll
  for (int mf = 0; mf < 2; ++mf)
#pragma unroll
    for (int n = 0; n < 3; ++n) {
      const int col = n * 16 + lm;
      if (col < DH_) {
#pragma unroll
        for (int r = 0; r < 4; ++r) {
          const int row = wrow + mf * 16 + quad * 4 + r;
          QO[qbase + (size_t)row * IN_ + col] = f2bf(oacc[mf][n][r] * rl[mf][r]);
        }
      }
    }
}

// ---------------------------------------------------------------------------
extern "C" void kernel_launch(void* const* d_in, const int* in_sizes, int n_in,
                              void* d_out, int out_size, void* d_ws,
                              size_t ws_size, hipStream_t stream)
{
  const float* x   = (const float*)d_in[0];
  const float* ctx = (const float*)d_in[1];
  const float* Wq  = (const float*)d_in[2];
  const float* Wk  = (const float*)d_in[3];
  const float* Wv  = (const float*)d_in[4];
  const float* Wo  = (const float*)d_in[5];
  const float* bo  = (const float*)d_in[6];
  const float* gq  = (const float*)d_in[7];
  const float* gk  = (const float*)d_in[8];
  const float* gv  = (const float*)d_in[9];
  const float* go  = (const float*)d_in[10];
  float* out = (float*)d_out;

  // Workspace carve-up (89,276,416 B total; harness gives >= 90 MB):
  //   q_ws: [131072, 320] bf16  (Q, overwritten in-place with O)
  //   Khb : [32, 8, 80, 64] bf16 (zero-padded K)
  //   Vtb : [32, 8, 48, 96] bf16 (zero-padded V^T)
  //   Wqb, Wob: [320, 320] bf16
  //   Wkb, Wvb: [320, 768] bf16 — ALIASED over the head of q_ws. They are
  //   only live between wcvt and kv_mfma; q_ws is first written by
  //   gemm_strip<0>, which is stream-ordered after kv_mfma.
  char* ws = (char*)d_ws;
  unsigned short* q_ws = (unsigned short*)ws;
  size_t off = (size_t)M_ * IN_ * 2;
  unsigned short* Khb = (unsigned short*)(ws + off); off += (size_t)B_ * H_ * NKP_ * KQ_ * 2;
  unsigned short* Vtb = (unsigned short*)(ws + off); off += (size_t)B_ * H_ * DHP_ * NKP2_ * 2;
  unsigned short* Wqb = (unsigned short*)(ws + off); off += (size_t)IN_ * IN_ * 2;
  unsigned short* Wob = (unsigned short*)(ws + off);
  unsigned short* Wkb = (unsigned short*)ws;                          // alias (dead before gemm0)
  unsigned short* Wvb = (unsigned short*)(ws + (size_t)IN_ * CD_ * 2);// alias

  hipMemsetAsync(Khb, 0, (size_t)B_ * H_ * NKP_ * KQ_ * 2, stream);
  hipMemsetAsync(Vtb, 0, (size_t)B_ * H_ * DHP_ * NKP2_ * 2, stream);

  wcvt<<<dim3(IN_ * CD_ / 4 / 256, 4), dim3(256), 0, stream>>>(
      Wq, Wo, Wk, Wv, Wqb, Wob, Wkb, Wvb);
  kv_mfma<<<dim3((MKV_ + 63) / 64, IN_ / 64, 2), dim3(256), 0, stream>>>(
      ctx, Wkb, Wvb, gk, gv, Khb, Vtb);
  gemm_strip<0><<<dim3(M_ / 64), dim3(256), 0, stream>>>(
      x, Wqb, gq, nullptr, q_ws);
  attn_mfma<<<dim3(NQ_ / QT_, H_, B_), dim3(256), 0, stream>>>(Khb, Vtb, q_ws);
  gemm_strip<1><<<dim3(M_ / 64), dim3(256), 0, stream>>>(
      q_ws, Wob, go, bo, out);
}

// Round 5
// 485.349 us; speedup vs baseline: 1.5588x; 1.5588x over previous
//
#include <hip/hip_runtime.h>

#define B_   32
#define NQ_  4096
#define NK_  77
#define H_   8
#define DH_  40
#define IN_  320
#define CD_  768
#define M_   (B_ * NQ_)   // 131072 rows
#define MKV_ (B_ * NK_)   // 2464 context rows

#define NKP_  80    // keys padded for score n-tiles
#define NKP2_ 96    // keys padded for PV k-steps
#define DHP_  48    // dims padded for PV n-tiles
#define KQ_   64    // qk k-dim padded (40 -> 64)

typedef __attribute__((ext_vector_type(8))) short bf16x8;
typedef __attribute__((ext_vector_type(4))) float f32x4;
typedef unsigned short ushort_t;

__device__ __forceinline__ unsigned short f2bf(float f) {
  union { float f; unsigned int i; } v; v.f = f;
  unsigned int i = v.i;
  i += 0x7fffu + ((i >> 16) & 1u);   // round-to-nearest-even
  return (unsigned short)(i >> 16);
}
__device__ __forceinline__ unsigned int pack2(float a, float b) {
  return (unsigned int)f2bf(a) | ((unsigned int)f2bf(b) << 16);
}

// async 16B global -> LDS (per-lane global addr, LDS dest = base + lane*16)
__device__ __forceinline__ void gl2lds16(const void* g, void* l) {
  __builtin_amdgcn_global_load_lds(
      (const __attribute__((address_space(1))) unsigned int*)g,
      (__attribute__((address_space(3))) unsigned int*)l,
      16, 0, 0);
}

// ---------------------------------------------------------------------------
// Convert weights to bf16 once. blockIdx.y: 0=Wq(320x320), 1=Wo(320x320),
// 2=Wk(320x768), 3=Wv(320x768).
// ---------------------------------------------------------------------------
__global__ __launch_bounds__(256) void wcvt(
    const float* __restrict__ Wq, const float* __restrict__ Wo,
    const float* __restrict__ Wk, const float* __restrict__ Wv,
    unsigned short* __restrict__ Wqb, unsigned short* __restrict__ Wob,
    unsigned short* __restrict__ Wkb, unsigned short* __restrict__ Wvb)
{
  const int i = blockIdx.x * 256 + threadIdx.x;   // float4 index
  const float* src;
  unsigned short* dst;
  int n;
  switch (blockIdx.y) {
    case 0:  src = Wq; dst = Wqb; n = IN_ * IN_ / 4; break;   // 25600
    case 1:  src = Wo; dst = Wob; n = IN_ * IN_ / 4; break;   // 25600
    case 2:  src = Wk; dst = Wkb; n = IN_ * CD_ / 4; break;   // 61440
    default: src = Wv; dst = Wvb; n = IN_ * CD_ / 4; break;   // 61440
  }
  if (i >= n) return;
  const float4 v = ((const float4*)src)[i];
  uint2 p; p.x = pack2(v.x, v.y); p.y = pack2(v.z, v.w);
  ((uint2*)dst)[i] = p;
}

// ---------------------------------------------------------------------------
// K/V projection as MFMA GEMM.
// C[2464,320] = ctx[2464,768] @ W[320,768]^T, tile 64x64, BK=32, row-guarded
// to M=2496. blockIdx.z: 0 -> K (scatter into Khb), 1 -> V (scatter into Vtb).
//   Khb: [B, H, 80, 64] bf16   (K rows; rows>=77 and cols>=40 stay zero)
//   Vtb: [B, H, 48, 96] bf16   (V transposed; rows>=40 and cols>=77 stay zero)
// Buffers pre-zeroed with hipMemsetAsync; epilogue fuses gamma + layout.
// ---------------------------------------------------------------------------
__global__ __launch_bounds__(256) void kv_mfma(
    const float* __restrict__ ctx, const unsigned short* __restrict__ Wkb,
    const unsigned short* __restrict__ Wvb, const float* __restrict__ gk,
    const float* __restrict__ gv, unsigned short* __restrict__ Khb,
    unsigned short* __restrict__ Vtb)
{
  constexpr int LDA = 40;   // bf16 elems per LDS row (32 + 8 pad)
  __shared__ alignas(16) unsigned short As[64 * LDA];
  __shared__ alignas(16) unsigned short Bs[64 * LDA];
  const int m0 = blockIdx.x * 64;       // 39 tiles cover 2496 >= 2464
  const int n0 = blockIdx.y * 64;       // 5 tiles cover 320
  const int isV = blockIdx.z;
  const unsigned short* Wb = isV ? Wvb : Wkb;
  const int tid = threadIdx.x;
  const int wave = tid >> 6;
  const int lane = tid & 63;
  const int lm = lane & 15;
  const int quad = lane >> 4;

  f32x4 acc0 = {0.f, 0.f, 0.f, 0.f};
  f32x4 acc1 = acc0, acc2 = acc0, acc3 = acc0;

  for (int k0 = 0; k0 < CD_; k0 += 32) {
    // stage A: 64 rows x 32 k, fp32 -> bf16, zero rows >= 2464
#pragma unroll
    for (int c = tid; c < 512; c += 256) {
      const int row = c >> 3, kq = (c & 7) << 2;
      const int fr = m0 + row;
      float4 v = {0.f, 0.f, 0.f, 0.f};
      if (fr < MKV_)
        v = *(const float4*)(ctx + (size_t)fr * CD_ + k0 + kq);
      uint2 p; p.x = pack2(v.x, v.y); p.y = pack2(v.z, v.w);
      *(uint2*)(&As[row * LDA + kq]) = p;
    }
    // stage B: 64 W rows x 32 k (bf16, contiguous uint4)
    {
      const int row = tid >> 2, kq = (tid & 3) << 3;
      *(uint4*)(&Bs[row * LDA + kq]) =
          *(const uint4*)(Wb + (size_t)(n0 + row) * CD_ + k0 + kq);
    }
    __syncthreads();
    const bf16x8 a  = *(const bf16x8*)(&As[(wave * 16 + lm) * LDA + quad * 8]);
    const bf16x8 b0 = *(const bf16x8*)(&Bs[( 0 + lm) * LDA + quad * 8]);
    const bf16x8 b1 = *(const bf16x8*)(&Bs[(16 + lm) * LDA + quad * 8]);
    const bf16x8 b2 = *(const bf16x8*)(&Bs[(32 + lm) * LDA + quad * 8]);
    const bf16x8 b3 = *(const bf16x8*)(&Bs[(48 + lm) * LDA + quad * 8]);
    acc0 = __builtin_amdgcn_mfma_f32_16x16x32_bf16(a, b0, acc0, 0, 0, 0);
    acc1 = __builtin_amdgcn_mfma_f32_16x16x32_bf16(a, b1, acc1, 0, 0, 0);
    acc2 = __builtin_amdgcn_mfma_f32_16x16x32_bf16(a, b2, acc2, 0, 0, 0);
    acc3 = __builtin_amdgcn_mfma_f32_16x16x32_bf16(a, b3, acc3, 0, 0, 0);
    __syncthreads();
  }

  const float* g = isV ? gv : gk;
  const f32x4 accs[4] = {acc0, acc1, acc2, acc3};
#pragma unroll
  for (int t = 0; t < 4; ++t) {
    const int col = n0 + t * 16 + lm;
    const int h = col / DH_, d = col % DH_;
    const float gc = g[col];
#pragma unroll
    for (int r = 0; r < 4; ++r) {
      const int row = m0 + wave * 16 + quad * 4 + r;
      if (row < MKV_) {
        const int bb = row / NK_, pos = row % NK_;
        const unsigned short val = f2bf(accs[t][r] * gc);
        if (!isV)
          Khb[((size_t)(bb * H_ + h) * NKP_ + pos) * KQ_ + d] = val;
        else
          Vtb[((size_t)(bb * H_ + h) * DHP_ + d) * NKP2_ + pos] = val;
      }
    }
  }
}

// ---------------------------------------------------------------------------
// Strip GEMM v4: C[M,320] = A[M,320] @ W[320,320]^T.
// Block = 64 rows x full 320 cols (A fetched once; a[10] = 40 VGPR, proven
// live at R2's 68-VGPR allocation). B staged via global_load_lds (zero
// staging VGPRs) into a double-buffered 2 x [32 rows x 320] chunk with an
// XOR swizzle (byte col c stored at c ^ ((row&7)<<4), applied by permuting
// the per-lane GLOBAL source address; LDS dest stays linear as the
// instruction requires). ds_write: 64 lanes x 16B consecutive = conflict-
// free; ds_read: swizzle breaks the 640B-row 16-way conflict to ~2-way.
// Pipeline: stage chunk nc+1, s_waitcnt vmcnt(5) (only chunk nc's loads,
// issued a full compute-phase earlier, are drained), raw s_barrier,
// 20 MFMA, epilogue, s_barrier. LDS 40 KB -> 4 blocks/CU.
// MODE 0: A = x fp32 (convert in regs), C = Q bf16, *gamma.
// MODE 1: A = O bf16 (ws), C = d_out fp32, (+bias)*gamma.
// ---------------------------------------------------------------------------
template <int MODE>
__global__ __launch_bounds__(256) void gemm_strip(
    const void* __restrict__ Ap, const unsigned short* __restrict__ Wb,
    const float* __restrict__ gamma, const float* __restrict__ bias,
    void* __restrict__ Cp)
{
  __shared__ alignas(16) unsigned short Bs[2 * 32 * 320];   // 40 KB dbuf
  const int m0 = blockIdx.x * 64;
  const int tid = threadIdx.x;
  const int wave = tid >> 6;
  const int lane = tid & 63;
  const int lm = lane & 15;
  const int quad = lane >> 4;
  const int arow = m0 + wave * 16 + lm;

  // ---- staging source offsets (bytes within a 20480 B chunk), j=0..4 ----
  // linear LDS dest D -> source r*640 + (c ^ ((r&7)<<4)); XOR is its own
  // inverse, so reads with the same XOR see W[r][c].
  unsigned soff[5];
#pragma unroll
  for (int j = 0; j < 5; ++j) {
    const unsigned D = (unsigned)(j * 4096 + wave * 1024 + lane * 16);
    const unsigned r = D / 640u, c = D - r * 640u;
    soff[j] = r * 640u + (c ^ ((r & 7u) << 4));
  }
  const char* wbase = (const char*)Wb;

  // ---- stage chunk 0 -> buf 0 ----
#pragma unroll
  for (int j = 0; j < 5; ++j)
    gl2lds16(wbase + soff[j], &Bs[j * 2048 + wave * 512]);

  // ---- A fragments: full K=320 in registers (10 frags = 40 VGPR) ----
  bf16x8 a[10];
  if (MODE == 0) {
    const float* A = (const float*)Ap;
    const float* rp = A + (size_t)arow * IN_ + quad * 8;
#pragma unroll
    for (int kf = 0; kf < 10; ++kf) {
      const float4 v0 = *(const float4*)(rp + kf * 32);
      const float4 v1 = *(const float4*)(rp + kf * 32 + 4);
      union { uint4 u; bf16x8 h; } cv;
      cv.u.x = pack2(v0.x, v0.y); cv.u.y = pack2(v0.z, v0.w);
      cv.u.z = pack2(v1.x, v1.y); cv.u.w = pack2(v1.z, v1.w);
      a[kf] = cv.h;
    }
  } else {
    const unsigned short* A = (const unsigned short*)Ap;
    const unsigned short* rp = A + (size_t)arow * IN_ + quad * 8;
#pragma unroll
    for (int kf = 0; kf < 10; ++kf)
      a[kf] = *(const bf16x8*)(rp + kf * 32);
  }

  // ---- per-lane read bases (byte offsets into a chunk) ----
  // frag(nf,kf): row = nf*16+lm, byte = row*640 + ((q ^ (lm&7))<<4),
  // q = kf*4+quad  =>  base(nf) + ((kf ^ kb)<<6), kb = (lm>>2)&1.
  const unsigned mask = (unsigned)(lm & 7);
  const unsigned kb = mask >> 2;
  const unsigned rb0 = (unsigned)(lm * 640) + (((unsigned)quad ^ (mask & 3u)) << 4);
  const unsigned rb1 = rb0 + 16 * 640;
  const char* BsB = (const char*)Bs;

  for (int nc = 0; nc < 10; ++nc) {
    const int cur = nc & 1;
    if (nc < 9) {   // stage chunk nc+1 into the other buffer
      const char* src = wbase + (unsigned)(nc + 1) * 20480u;
#pragma unroll
      for (int j = 0; j < 5; ++j)
        gl2lds16(src + soff[j], &Bs[(cur ^ 1) * 10240 + j * 2048 + wave * 512]);
      asm volatile("s_waitcnt vmcnt(5)" ::: "memory");
    } else {
      asm volatile("s_waitcnt vmcnt(0)" ::: "memory");
    }
    __builtin_amdgcn_s_barrier();
    asm volatile("" ::: "memory");

    f32x4 acc0 = {0.f, 0.f, 0.f, 0.f}, acc1 = acc0;
    const unsigned cbase = (unsigned)(cur * 20480);
#pragma unroll
    for (int kf = 0; kf < 10; ++kf) {
      const unsigned ko = ((unsigned)kf ^ kb) << 6;
      const bf16x8 b0 = *(const bf16x8*)(BsB + cbase + rb0 + ko);
      const bf16x8 b1 = *(const bf16x8*)(BsB + cbase + rb1 + ko);
      acc0 = __builtin_amdgcn_mfma_f32_16x16x32_bf16(a[kf], b0, acc0, 0, 0, 0);
      acc1 = __builtin_amdgcn_mfma_f32_16x16x32_bf16(a[kf], b1, acc1, 0, 0, 0);
    }

    // ---- epilogue for this 32-col chunk ----
#pragma unroll
    for (int nf = 0; nf < 2; ++nf) {
      const f32x4 av = nf ? acc1 : acc0;
      const int col = nc * 32 + nf * 16 + lm;
      const float g = gamma[col];
      if (MODE == 0) {
#pragma unroll
        for (int r = 0; r < 4; ++r) {
          const int row = m0 + wave * 16 + quad * 4 + r;
          ((unsigned short*)Cp)[(size_t)row * IN_ + col] = f2bf(av[r] * g);
        }
      } else {
        const float bbv = bias[col];
#pragma unroll
        for (int r = 0; r < 4; ++r) {
          const int row = m0 + wave * 16 + quad * 4 + r;
          ((float*)Cp)[(size_t)row * IN_ + col] = (av[r] + bbv) * g;
        }
      }
    }
    __builtin_amdgcn_s_barrier();   // all reads of buf[cur] done before its
    asm volatile("" ::: "memory");  // overwrite at the next iteration's stage
  }
}

// ---------------------------------------------------------------------------
// MFMA attention. Block = 256 thr (4 waves) handles (b, h, 128 q rows);
// each wave owns 32 rows (2 m-frags). S = Q.K^T (k 40->64), softmax in regs
// (shfl_xor over the 16 col-lanes), P -> LDS (C-layout -> A-layout), P.V with
// keys padded to 96 against V^T. O overwrites Q slice in ws (bf16).
// LDS: Qs[128x72] + Ks[80x72] overlaid later by Ps[4][32x104]; Vt[48x104].
// ---------------------------------------------------------------------------
#define QT_ 128
__global__ __launch_bounds__(256) void attn_mfma(
    const unsigned short* __restrict__ Khb,
    const unsigned short* __restrict__ Vtb,
    unsigned short* __restrict__ QO)
{
  __shared__ alignas(16) unsigned short smem[14976 + 48 * 104];
  unsigned short* Qs = smem;            // 128 x 72
  unsigned short* Ks = smem + 128 * 72; // 80 x 72
  unsigned short* Vt = smem + 14976;    // 48 x 104
  unsigned short* Ps = smem;            // overlays Qs/Ks: wave w at w*32*104

  const int b = blockIdx.z, h = blockIdx.y, qt = blockIdx.x;
  const int tid = threadIdx.x;
  const int row0 = qt * QT_;
  const size_t qbase = ((size_t)b * NQ_ + row0) * IN_ + h * DH_;

  // ---- stage Q (bf16, zero-pad cols 40..71) ----
  for (int i = tid; i < QT_ * 9; i += 256) {
    const int row = i / 9, seg = i % 9;
    uint4 v = {0u, 0u, 0u, 0u};
    if (seg < 5)
      v = *(const uint4*)(QO + qbase + (size_t)row * IN_ + seg * 8);
    *(uint4*)(&Qs[row * 72 + seg * 8]) = v;
  }
  // ---- stage K [80x64] -> [80x72] (zero-pad cols 64..71) ----
  {
    const unsigned short* src = Khb + (size_t)(b * H_ + h) * NKP_ * KQ_;
    for (int i = tid; i < NKP_ * 9; i += 256) {
      const int row = i / 9, seg = i % 9;
      uint4 v = {0u, 0u, 0u, 0u};
      if (seg < 8) v = *(const uint4*)(src + row * KQ_ + seg * 8);
      *(uint4*)(&Ks[row * 72 + seg * 8]) = v;
    }
  }
  // ---- stage V^T [48x96] -> [48x104] (cols 96..103 never read) ----
  {
    const unsigned short* src = Vtb + (size_t)(b * H_ + h) * DHP_ * NKP2_;
    for (int i = tid; i < DHP_ * 12; i += 256) {
      const int row = i / 12, seg = i % 12;
      *(uint4*)(&Vt[row * 104 + seg * 8]) =
          *(const uint4*)(src + row * NKP2_ + seg * 8);
    }
  }
  __syncthreads();

  const int wave = tid >> 6;
  const int lane = tid & 63;
  const int lm = lane & 15;
  const int quad = lane >> 4;
  const int wrow = wave * 32;   // wave's 32-row window within the 128-row tile

  // ---- S = Q.K^T ----
  f32x4 sacc[2][5];
#pragma unroll
  for (int mf = 0; mf < 2; ++mf)
#pragma unroll
    for (int t = 0; t < 5; ++t) sacc[mf][t] = (f32x4){0.f, 0.f, 0.f, 0.f};

#pragma unroll
  for (int k = 0; k < 2; ++k) {
    bf16x8 aq[2];
#pragma unroll
    for (int mf = 0; mf < 2; ++mf)
      aq[mf] = *(const bf16x8*)(&Qs[(wrow + mf * 16 + lm) * 72 + k * 32 + quad * 8]);
#pragma unroll
    for (int t = 0; t < 5; ++t) {
      const bf16x8 bk = *(const bf16x8*)(&Ks[(t * 16 + lm) * 72 + k * 32 + quad * 8]);
#pragma unroll
      for (int mf = 0; mf < 2; ++mf)
        sacc[mf][t] = __builtin_amdgcn_mfma_f32_16x16x32_bf16(aq[mf], bk, sacc[mf][t], 0, 0, 0);
    }
  }

  // ---- softmax (rows = quad*4+r within each 16-row m-frag) ----
  const float scale = 0.15811388300841897f;   // 1/sqrt(40)
  float sv[2][5][4];
  float rl[2][4];
#pragma unroll
  for (int mf = 0; mf < 2; ++mf) {
#pragma unroll
    for (int t = 0; t < 5; ++t)
#pragma unroll
      for (int r = 0; r < 4; ++r) {
        float v = sacc[mf][t][r] * scale;
        if (t == 4 && lm >= 13) v = -1e30f;   // mask keys 77..79
        sv[mf][t][r] = v;
      }
#pragma unroll
    for (int r = 0; r < 4; ++r) {
      float m = sv[mf][0][r];
#pragma unroll
      for (int t = 1; t < 5; ++t) m = fmaxf(m, sv[mf][t][r]);
#pragma unroll
      for (int d = 1; d < 16; d <<= 1) m = fmaxf(m, __shfl_xor(m, d));
      float l = 0.f;
#pragma unroll
      for (int t = 0; t < 5; ++t) {
        const float e = __expf(sv[mf][t][r] - m);
        sv[mf][t][r] = e;
        l += e;
      }
#pragma unroll
      for (int d = 1; d < 16; d <<= 1) l += __shfl_xor(l, d);
      rl[mf][r] = 1.f / l;
    }
  }

  __syncthreads();   // all S-phase reads of Qs/Ks done before Ps overlay

  // ---- P -> LDS (A-layout source), zero cols 80..95 (keys pad for PV) ----
  unsigned short* Pw = Ps + wave * 32 * 104;
#pragma unroll
  for (int mf = 0; mf < 2; ++mf)
#pragma unroll
    for (int t = 0; t < 5; ++t)
#pragma unroll
      for (int r = 0; r < 4; ++r)
        Pw[(mf * 16 + quad * 4 + r) * 104 + t * 16 + lm] = f2bf(sv[mf][t][r]);
  {
    const int row = lane >> 1, half = lane & 1;
    *(uint4*)(&Pw[row * 104 + 80 + half * 8]) = (uint4){0u, 0u, 0u, 0u};
  }
  __syncthreads();

  // ---- O = P.V  (K = 96 keys, N = 48 dims) ----
  f32x4 oacc[2][3];
#pragma unroll
  for (int mf = 0; mf < 2; ++mf)
#pragma unroll
    for (int n = 0; n < 3; ++n) oacc[mf][n] = (f32x4){0.f, 0.f, 0.f, 0.f};

#pragma unroll
  for (int k = 0; k < 3; ++k) {
    bf16x8 ap[2];
#pragma unroll
    for (int mf = 0; mf < 2; ++mf)
      ap[mf] = *(const bf16x8*)(&Pw[(mf * 16 + lm) * 104 + k * 32 + quad * 8]);
#pragma unroll
    for (int n = 0; n < 3; ++n) {
      const bf16x8 bv = *(const bf16x8*)(&Vt[(n * 16 + lm) * 104 + k * 32 + quad * 8]);
#pragma unroll
      for (int mf = 0; mf < 2; ++mf)
        oacc[mf][n] = __builtin_amdgcn_mfma_f32_16x16x32_bf16(ap[mf], bv, oacc[mf][n], 0, 0, 0);
    }
  }

  // ---- store O (bf16) over the Q slice ----
#pragma unroll
  for (int mf = 0; mf < 2; ++mf)
#pragma unroll
    for (int n = 0; n < 3; ++n) {
      const int col = n * 16 + lm;
      if (col < DH_) {
#pragma unroll
        for (int r = 0; r < 4; ++r) {
          const int row = wrow + mf * 16 + quad * 4 + r;
          QO[qbase + (size_t)row * IN_ + col] = f2bf(oacc[mf][n][r] * rl[mf][r]);
        }
      }
    }
}

// ---------------------------------------------------------------------------
extern "C" void kernel_launch(void* const* d_in, const int* in_sizes, int n_in,
                              void* d_out, int out_size, void* d_ws,
                              size_t ws_size, hipStream_t stream)
{
  const float* x   = (const float*)d_in[0];
  const float* ctx = (const float*)d_in[1];
  const float* Wq  = (const float*)d_in[2];
  const float* Wk  = (const float*)d_in[3];
  const float* Wv  = (const float*)d_in[4];
  const float* Wo  = (const float*)d_in[5];
  const float* bo  = (const float*)d_in[6];
  const float* gq  = (const float*)d_in[7];
  const float* gk  = (const float*)d_in[8];
  const float* gv  = (const float*)d_in[9];
  const float* go  = (const float*)d_in[10];
  float* out = (float*)d_out;

  // Workspace carve-up (89,276,416 B total; harness gives >= 90 MB):
  //   q_ws: [131072, 320] bf16  (Q, overwritten in-place with O)
  //   Khb : [32, 8, 80, 64] bf16 (zero-padded K)
  //   Vtb : [32, 8, 48, 96] bf16 (zero-padded V^T)
  //   Wqb, Wob: [320, 320] bf16
  //   Wkb, Wvb: [320, 768] bf16 — ALIASED over the head of q_ws. They are
  //   only live between wcvt and kv_mfma; q_ws is first written by
  //   gemm_strip<0>, which is stream-ordered after kv_mfma.
  char* ws = (char*)d_ws;
  unsigned short* q_ws = (unsigned short*)ws;
  size_t off = (size_t)M_ * IN_ * 2;
  unsigned short* Khb = (unsigned short*)(ws + off); off += (size_t)B_ * H_ * NKP_ * KQ_ * 2;
  unsigned short* Vtb = (unsigned short*)(ws + off); off += (size_t)B_ * H_ * DHP_ * NKP2_ * 2;
  unsigned short* Wqb = (unsigned short*)(ws + off); off += (size_t)IN_ * IN_ * 2;
  unsigned short* Wob = (unsigned short*)(ws + off);
  unsigned short* Wkb = (unsigned short*)ws;                          // alias (dead before gemm0)
  unsigned short* Wvb = (unsigned short*)(ws + (size_t)IN_ * CD_ * 2);// alias

  hipMemsetAsync(Khb, 0, (size_t)B_ * H_ * NKP_ * KQ_ * 2, stream);
  hipMemsetAsync(Vtb, 0, (size_t)B_ * H_ * DHP_ * NKP2_ * 2, stream);

  wcvt<<<dim3(IN_ * CD_ / 4 / 256, 4), dim3(256), 0, stream>>>(
      Wq, Wo, Wk, Wv, Wqb, Wob, Wkb, Wvb);
  kv_mfma<<<dim3((MKV_ + 63) / 64, IN_ / 64, 2), dim3(256), 0, stream>>>(
      ctx, Wkb, Wvb, gk, gv, Khb, Vtb);
  gemm_strip<0><<<dim3(M_ / 64), dim3(256), 0, stream>>>(
      x, Wqb, gq, nullptr, q_ws);
  attn_mfma<<<dim3(NQ_ / QT_, H_, B_), dim3(256), 0, stream>>>(Khb, Vtb, q_ws);
  gemm_strip<1><<<dim3(M_ / 64), dim3(256), 0, stream>>>(
      q_ws, Wob, go, bo, out);
}